// Round 5
// baseline (10741.645 us; speedup 1.0000x reference)
//
#include <hip/hip_runtime.h>
#include <hip/hip_bf16.h>

#define SEQ 512
#define BATCH 64
#define HID 1024

typedef __bf16 bf16x8 __attribute__((ext_vector_type(8)));
typedef __bf16 bf16x4 __attribute__((ext_vector_type(4)));
typedef float f32x4 __attribute__((ext_vector_type(4)));
typedef unsigned uint32x4 __attribute__((ext_vector_type(4)));

__device__ __forceinline__ float sigm(float x) { return 1.0f / (1.0f + __expf(-x)); }
__device__ __forceinline__ float tanh_(float x) { return 2.0f / (1.0f + __expf(-2.0f * x)) - 1.0f; }

// device-coherent (bypass L1/L2 -> LLC coherence point) helpers
__device__ __forceinline__ void cload4(uint32x4* d, const unsigned* p) {
    asm volatile("global_load_dwordx4 %0, %1, off sc0 sc1" : "=v"(*d) : "v"(p));
}
__device__ __forceinline__ void cstore_b32(unsigned* p, unsigned v) {
    asm volatile("global_store_dword %0, %1, off sc0 sc1" :: "v"(p), "v"(v));
}
#define WAITV(N) do { asm volatile("s_waitcnt vmcnt(" #N ")" ::: "memory"); \
                      __builtin_amdgcn_sched_barrier(0); } while (0)

// ---------------------------------------------------------------------------
// f32 -> bf16 conversion (n multiple of 4)
// ---------------------------------------------------------------------------
__global__ __launch_bounds__(256) void cvt_f32_bf16(const float* __restrict__ src,
                                                     __bf16* __restrict__ dst, int n)
{
    int i = (blockIdx.x * 256 + threadIdx.x) * 4;
    if (i < n) {
        f32x4 v = *(const f32x4*)(src + i);
        bf16x4 o;
        #pragma unroll
        for (int j = 0; j < 4; ++j) o[j] = (__bf16)v[j];
        *(bf16x4*)(dst + i) = o;
    }
}

// ---------------------------------------------------------------------------
// Phase A (unchanged): G[m][n] = x-parts of gates, m = t*BATCH+b.
// ---------------------------------------------------------------------------
template <bool XB>
__global__ __launch_bounds__(256) void gru_phaseA(
    const float* __restrict__ xf, const __bf16* __restrict__ xb,
    const __bf16* __restrict__ Wrb, const __bf16* __restrict__ Wub,
    const __bf16* __restrict__ Wxb,
    const float* __restrict__ br, const float* __restrict__ bu,
    const float* __restrict__ bx, __bf16* __restrict__ G)
{
    const int NT = (3 * HID) / 64;
    int mt = blockIdx.x / NT;
    int nt = blockIdx.x % NT;
    int m0 = mt * 128, n0 = nt * 64;

    const __bf16* W; const float* bias; int wstride, nb;
    if (n0 < HID)          { W = Wrb; bias = br; wstride = 2 * HID; nb = n0; }
    else if (n0 < 2 * HID) { W = Wub; bias = bu; wstride = 2 * HID; nb = n0 - HID; }
    else                   { W = Wxb; bias = bx; wstride = HID;     nb = n0 - 2 * HID; }

    int lane = threadIdx.x & 63, w = threadIdx.x >> 6;
    int llo = lane & 15, lhi = lane >> 4;
    int wm = (w & 1) * 64, wn = (w >> 1) * 32;

    f32x4 acc[4][2] = {};
    #pragma unroll 2
    for (int k0 = 0; k0 < HID; k0 += 32) {
        int ka = k0 + lhi * 8;
        bf16x8 af[4], bfr[2];
        #pragma unroll
        for (int mi = 0; mi < 4; ++mi) {
            size_t roff = (size_t)(m0 + wm + mi * 16 + llo) * HID + ka;
            if (XB) {
                af[mi] = *(const bf16x8*)(xb + roff);
            } else {
                f32x4 lo = *(const f32x4*)(xf + roff);
                f32x4 hi = *(const f32x4*)(xf + roff + 4);
                #pragma unroll
                for (int jj = 0; jj < 4; ++jj) { af[mi][jj] = (__bf16)lo[jj]; af[mi][4 + jj] = (__bf16)hi[jj]; }
            }
        }
        #pragma unroll
        for (int ni = 0; ni < 2; ++ni)
            bfr[ni] = *(const bf16x8*)(W + (size_t)(nb + wn + ni * 16 + llo) * wstride + ka);
        #pragma unroll
        for (int mi = 0; mi < 4; ++mi)
            #pragma unroll
            for (int ni = 0; ni < 2; ++ni)
                acc[mi][ni] = __builtin_amdgcn_mfma_f32_16x16x32_bf16(af[mi], bfr[ni], acc[mi][ni], 0, 0, 0);
    }
    #pragma unroll
    for (int ni = 0; ni < 2; ++ni) {
        int colg = n0 + wn + ni * 16 + llo;
        float bv = bias[nb + wn + ni * 16 + llo];
        #pragma unroll
        for (int mi = 0; mi < 4; ++mi) {
            #pragma unroll
            for (int i = 0; i < 4; ++i) {
                int row = m0 + wm + mi * 16 + lhi * 4 + i;
                G[(size_t)row * (3 * HID) + colg] = (__bf16)(acc[mi][ni][i] + bv);
            }
        }
    }
}

// ---------------------------------------------------------------------------
// Init: tagged h buffers. parity0 = {tag=0, bf16(prev)}; parity1 = tag 0xFFFF
// (never matches any expected tag 0..512 -> forces retry until fresh write;
//  also kills cross-replay stale-tag aliasing).
// ---------------------------------------------------------------------------
__global__ __launch_bounds__(256) void gru_init(const float* __restrict__ prev,
                                                unsigned* __restrict__ hg)
{
    int i = blockIdx.x * 256 + threadIdx.x;
    if (i < BATCH * HID) {
        unsigned short b = __builtin_bit_cast(unsigned short, (__bf16)prev[i]);
        hg[i] = (unsigned)b;                       // tag 0 | value
        hg[BATCH * HID + i] = 0xFFFF0000u;         // invalid tag
    }
}

// ---------------------------------------------------------------------------
// Phase B v4: self-timed dataflow recurrence. 256 WGs x 1 wave.
// WG g: col-group j = g&63 (16 hidden cols), row-group rg = g>>6 (16 batch rows).
// Each wave: all 3 gates, full K, for its 16x16 tile. No barriers, no flags:
// h is exchanged as tagged dwords {step:16 | bf16:16}; consumers retry on
// tag mismatch. W_r frags in VGPR (static), W_u/W_o in 64KB swizzled LDS.
// f32 h master + gate x-parts + out values all in registers.
// ---------------------------------------------------------------------------
__global__ __launch_bounds__(64, 1) void gru_phaseB(
    const __bf16* __restrict__ Wrb, const __bf16* __restrict__ Wub,
    const __bf16* __restrict__ Wob, const float* __restrict__ bo,
    const float* __restrict__ prev, const __bf16* __restrict__ G,
    unsigned* __restrict__ hg, float* __restrict__ out)
{
    __shared__ char UO[65536];   // rows 0-15: W_u h-part, rows 16-31: W_o (XOR-swizzled)

    const int g = blockIdx.x;
    const int j = g & 63, rg = g >> 6;
    const int lane = threadIdx.x & 63;
    const int llo = lane & 15, lhi = lane >> 4;
    const int swz = (llo & 7) << 4;

    // ---- stage W_u, W_o into LDS (once) ----
    for (int q = 0; q < 64; ++q) {
        int c = q * 64 + lane;
        int r = c >> 7;                  // 0..31
        int koff = (c & 127) * 8;
        bf16x8 v;
        if (r < 16) v = *(const bf16x8*)(Wub + (size_t)(16 * j + r) * (2 * HID) + HID + koff);
        else        v = *(const bf16x8*)(Wob + (size_t)(16 * j + (r - 16)) * HID + koff);
        int byte = (r * 2048 + koff * 2) ^ ((r & 7) << 4);
        *(bf16x8*)(UO + byte) = v;
    }
    // ---- stage W_r fragments into VGPRs (static, 128 regs) ----
    bf16x8 wR[32];
    #pragma unroll
    for (int kk = 0; kk < 32; ++kk)
        wR[kk] = *(const bf16x8*)(Wrb + (size_t)(16 * j + llo) * (2 * HID) + HID + kk * 32 + lhi * 8);
    __syncthreads();

    // ---- per-lane state in registers ----
    float hf[4], pr[4], pu[4], px[4];
    #pragma unroll
    for (int i = 0; i < 4; ++i) {
        int row = 16 * rg + lhi * 4 + i;
        hf[i] = prev[(size_t)row * HID + 16 * j + llo];
        const __bf16* Gp = G + (size_t)row * (3 * HID) + 16 * j + llo;
        pr[i] = (float)Gp[0]; pu[i] = (float)Gp[HID]; px[i] = (float)Gp[2 * HID];
    }
    const float bov = bo[16 * j + llo];

#define LOADB(BUF, KB) do { \
    cload4(&BUF[0], hk + (KB + 0) * 32);     cload4(&BUF[1], hk + (KB + 0) * 32 + 4); \
    cload4(&BUF[2], hk + (KB + 1) * 32);     cload4(&BUF[3], hk + (KB + 1) * 32 + 4); \
    cload4(&BUF[4], hk + (KB + 2) * 32);     cload4(&BUF[5], hk + (KB + 2) * 32 + 4); \
    cload4(&BUF[6], hk + (KB + 3) * 32);     cload4(&BUF[7], hk + (KB + 3) * 32 + 4); } while (0)

#define CONSK(D0, D1, KK, AR, AU, AO) do { \
    unsigned d0 = (D0).x, d1 = (D0).y, d2 = (D0).z, d3 = (D0).w; \
    unsigned d4 = (D1).x, d5 = (D1).y, d6 = (D1).z, d7 = (D1).w; \
    bad |= (d0 ^ texp) | (d1 ^ texp) | (d2 ^ texp) | (d3 ^ texp) \
         | (d4 ^ texp) | (d5 ^ texp) | (d6 ^ texp) | (d7 ^ texp); \
    uint32x4 rp = { (d0 & 0xffffu) | (d1 << 16), (d2 & 0xffffu) | (d3 << 16), \
                    (d4 & 0xffffu) | (d5 << 16), (d6 & 0xffffu) | (d7 << 16) }; \
    bf16x8 af = __builtin_bit_cast(bf16x8, rp); \
    int kb_ = (KK) * 64 + lhi * 16; \
    bf16x8 bu_ = *(const bf16x8*)(UO + ((llo * 2048 + kb_) ^ swz)); \
    bf16x8 bo_ = *(const bf16x8*)(UO + 32768 + ((llo * 2048 + kb_) ^ swz)); \
    AR = __builtin_amdgcn_mfma_f32_16x16x32_bf16(af, wR[KK], AR, 0, 0, 0); \
    AU = __builtin_amdgcn_mfma_f32_16x16x32_bf16(af, bu_, AU, 0, 0, 0); \
    AO = __builtin_amdgcn_mfma_f32_16x16x32_bf16(af, bo_, AO, 0, 0, 0); } while (0)

#define CONSB(BUF, KB) do { \
    CONSK(BUF[0], BUF[1], KB + 0, aR0, aU0, aO0); \
    CONSK(BUF[2], BUF[3], KB + 1, aR1, aU1, aO1); \
    CONSK(BUF[4], BUF[5], KB + 2, aR0, aU0, aO0); \
    CONSK(BUF[6], BUF[7], KB + 3, aR1, aU1, aO1); } while (0)

    for (int t = 0; t < SEQ; ++t) {
        const unsigned* hk = hg + ((size_t)(t & 1) << 16) + (size_t)(16 * rg + llo) * HID + lhi * 8;
        const unsigned texp = (unsigned)t << 16;
        f32x4 aR0, aR1, aU0, aU1, aO0, aO1;
        int guard = 0;
        for (;;) {
            unsigned bad = 0;
            aR0 = f32x4{0,0,0,0}; aR1 = f32x4{0,0,0,0};
            aU0 = f32x4{0,0,0,0}; aU1 = f32x4{0,0,0,0};
            aO0 = f32x4{0,0,0,0}; aO1 = f32x4{0,0,0,0};
            uint32x4 LA[8], LB[8];
            LOADB(LA, 0);  LOADB(LB, 4);  WAITV(8);
            CONSB(LA, 0);  LOADB(LA, 8);  WAITV(8);
            CONSB(LB, 4);  LOADB(LB, 12); WAITV(8);
            CONSB(LA, 8);  LOADB(LA, 16); WAITV(8);
            CONSB(LB, 12); LOADB(LB, 20); WAITV(8);
            CONSB(LA, 16); LOADB(LA, 24); WAITV(8);
            CONSB(LB, 20); LOADB(LB, 28); WAITV(8);
            CONSB(LA, 24); WAITV(0);
            CONSB(LB, 28);
            if (__all((int)((bad >> 16) == 0u))) break;
            if (++guard >= (1 << 11)) break;   // safety valve (never in correct runs)
        }
        f32x4 aR = aR0 + aR1, aU = aU0 + aU1, aO = aO0 + aO1;

        unsigned* hn = hg + ((size_t)((t + 1) & 1) << 16);
        const unsigned ntag = (unsigned)(t + 1) << 16;
        #pragma unroll
        for (int i = 0; i < 4; ++i) {
            int row = 16 * rg + lhi * 4 + i;
            float r = sigm(aR[i] + pr[i]);
            float u = sigm(aU[i] + pu[i]);
            float c = tanh_((aO[i] + bov) * r + px[i]);
            float hnew = (1.0f - u) * c + u * hf[i];
            hf[i] = hnew;
            unsigned short hb = __builtin_bit_cast(unsigned short, (__bf16)hnew);
            cstore_b32(hn + (size_t)row * HID + 16 * j + llo, ntag | (unsigned)hb);
        }
        // deferred (non-critical): out writes + G prefetch for t+1
        #pragma unroll
        for (int i = 0; i < 4; ++i) {
            int row = 16 * rg + lhi * 4 + i;
            __builtin_nontemporal_store(hf[i],
                out + (size_t)t * (BATCH * HID) + (size_t)row * HID + 16 * j + llo);
            if (t == SEQ - 1)
                __builtin_nontemporal_store(hf[i],
                    out + (size_t)SEQ * (BATCH * HID) + (size_t)row * HID + 16 * j + llo);
        }
        if (t + 1 < SEQ) {
            const __bf16* Gt = G + (size_t)(t + 1) * BATCH * (3 * HID);
            #pragma unroll
            for (int i = 0; i < 4; ++i) {
                int row = 16 * rg + lhi * 4 + i;
                const __bf16* Gp = Gt + (size_t)row * (3 * HID) + 16 * j + llo;
                pr[i] = (float)Gp[0]; pu[i] = (float)Gp[HID]; px[i] = (float)Gp[2 * HID];
            }
        }
    }
#undef LOADB
#undef CONSK
#undef CONSB
}

extern "C" void kernel_launch(void* const* d_in, const int* in_sizes, int n_in,
                              void* d_out, int out_size, void* d_ws, size_t ws_size,
                              hipStream_t stream) {
    (void)in_sizes; (void)n_in; (void)out_size;
    const float* x    = (const float*)d_in[0];
    const float* prev = (const float*)d_in[1];
    const float* Wr   = (const float*)d_in[2];
    const float* br   = (const float*)d_in[3];
    const float* Wu   = (const float*)d_in[4];
    const float* bu   = (const float*)d_in[5];
    const float* Wo   = (const float*)d_in[6];
    const float* bo   = (const float*)d_in[7];
    const float* Wx   = (const float*)d_in[8];
    const float* bx   = (const float*)d_in[9];
    float* out = (float*)d_out;

    // workspace layout (bytes)
    const size_t G_ELEMS  = (size_t)SEQ * BATCH * 3 * HID;
    const size_t WR_ELEMS = (size_t)HID * 2 * HID;
    const size_t WO_ELEMS = (size_t)HID * HID;
    char* ws = (char*)d_ws;
    size_t off = 0;
    __bf16* G   = (__bf16*)(ws + off); off += G_ELEMS * 2;
    __bf16* Wrb = (__bf16*)(ws + off); off += WR_ELEMS * 2;
    __bf16* Wub = (__bf16*)(ws + off); off += WR_ELEMS * 2;
    __bf16* Wob = (__bf16*)(ws + off); off += WO_ELEMS * 2;
    __bf16* Wxb = (__bf16*)(ws + off); off += WO_ELEMS * 2;
    unsigned* hg = (unsigned*)(ws + off); off += (size_t)2 * BATCH * HID * 4;  // tagged dwords
    const size_t X_ELEMS = (size_t)SEQ * BATCH * HID;
    bool use_xb = (ws_size >= off + X_ELEMS * 2);
    __bf16* xb = (__bf16*)(ws + off);

    cvt_f32_bf16<<<(int)(WR_ELEMS / 4 / 256), 256, 0, stream>>>(Wr, Wrb, (int)WR_ELEMS);
    cvt_f32_bf16<<<(int)(WR_ELEMS / 4 / 256), 256, 0, stream>>>(Wu, Wub, (int)WR_ELEMS);
    cvt_f32_bf16<<<(int)(WO_ELEMS / 4 / 256), 256, 0, stream>>>(Wo, Wob, (int)WO_ELEMS);
    cvt_f32_bf16<<<(int)(WO_ELEMS / 4 / 256), 256, 0, stream>>>(Wx, Wxb, (int)WO_ELEMS);
    if (use_xb)
        cvt_f32_bf16<<<(int)(X_ELEMS / 4 / 256), 256, 0, stream>>>(x, xb, (int)X_ELEMS);

    gru_init<<<(BATCH * HID) / 256, 256, 0, stream>>>(prev, hg);

    int gridA = (SEQ * BATCH / 128) * ((3 * HID) / 64);
    if (use_xb)
        gru_phaseA<true><<<gridA, 256, 0, stream>>>(x, xb, Wrb, Wub, Wxb, br, bu, bx, G);
    else
        gru_phaseA<false><<<gridA, 256, 0, stream>>>(x, xb, Wrb, Wub, Wxb, br, bu, bx, G);

    gru_phaseB<<<256, 64, 0, stream>>>(Wrb, Wub, Wob, bo, prev, G, hg, out);
}

// Round 6
// 3245.800 us; speedup vs baseline: 3.3094x; 3.3094x over previous
//
#include <hip/hip_runtime.h>
#include <hip/hip_bf16.h>

#define SEQ 512
#define BATCH 64
#define HID 1024

typedef __bf16 bf16x8 __attribute__((ext_vector_type(8)));
typedef __bf16 bf16x4 __attribute__((ext_vector_type(4)));
typedef float f32x4 __attribute__((ext_vector_type(4)));

__device__ __forceinline__ float sigm(float x) { return 1.0f / (1.0f + __expf(-x)); }
__device__ __forceinline__ float tanh_(float x) { return 2.0f / (1.0f + __expf(-2.0f * x)) - 1.0f; }

// device-coherent (LLC coherence point) helpers
__device__ __forceinline__ void cload_b128(bf16x8* d, const __bf16* p) {
    asm volatile("global_load_dwordx4 %0, %1, off sc0 sc1" : "=v"(*d) : "v"(p));
}
__device__ __forceinline__ void cstore_b16(__bf16* p, __bf16 v) {
    unsigned short uv = __builtin_bit_cast(unsigned short, v);
    asm volatile("global_store_short %0, %1, off sc0 sc1" :: "v"(p), "v"(uv));
}
__device__ __forceinline__ void cstore_b32(unsigned* p, unsigned v) {
    asm volatile("global_store_dword %0, %1, off sc0 sc1" :: "v"(p), "v"(v));
}
__device__ __forceinline__ unsigned cload_b32(const unsigned* p) {
    unsigned r;
    asm volatile("global_load_dword %0, %1, off sc0 sc1\n\ts_waitcnt vmcnt(0)"
                 : "=v"(r) : "v"(p) : "memory");
    __builtin_amdgcn_sched_barrier(0);
    return r;
}
__device__ __forceinline__ void vmcnt0() {
    asm volatile("s_waitcnt vmcnt(0)" ::: "memory");
    __builtin_amdgcn_sched_barrier(0);
}

// ---------------------------------------------------------------------------
// f32 -> bf16 conversion (n multiple of 4)
// ---------------------------------------------------------------------------
__global__ __launch_bounds__(256) void cvt_f32_bf16(const float* __restrict__ src,
                                                     __bf16* __restrict__ dst, int n)
{
    int i = (blockIdx.x * 256 + threadIdx.x) * 4;
    if (i < n) {
        f32x4 v = *(const f32x4*)(src + i);
        bf16x4 o;
        #pragma unroll
        for (int j = 0; j < 4; ++j) o[j] = (__bf16)v[j];
        *(bf16x4*)(dst + i) = o;
    }
}

// ---------------------------------------------------------------------------
// Phase A (unchanged): G[m][n] = x-parts of gates, m = t*BATCH+b.
// ---------------------------------------------------------------------------
template <bool XB>
__global__ __launch_bounds__(256) void gru_phaseA(
    const float* __restrict__ xf, const __bf16* __restrict__ xb,
    const __bf16* __restrict__ Wrb, const __bf16* __restrict__ Wub,
    const __bf16* __restrict__ Wxb,
    const float* __restrict__ br, const float* __restrict__ bu,
    const float* __restrict__ bx, __bf16* __restrict__ G)
{
    const int NT = (3 * HID) / 64;
    int mt = blockIdx.x / NT;
    int nt = blockIdx.x % NT;
    int m0 = mt * 128, n0 = nt * 64;

    const __bf16* W; const float* bias; int wstride, nb;
    if (n0 < HID)          { W = Wrb; bias = br; wstride = 2 * HID; nb = n0; }
    else if (n0 < 2 * HID) { W = Wub; bias = bu; wstride = 2 * HID; nb = n0 - HID; }
    else                   { W = Wxb; bias = bx; wstride = HID;     nb = n0 - 2 * HID; }

    int lane = threadIdx.x & 63, w = threadIdx.x >> 6;
    int llo = lane & 15, lhi = lane >> 4;
    int wm = (w & 1) * 64, wn = (w >> 1) * 32;

    f32x4 acc[4][2] = {};
    #pragma unroll 2
    for (int k0 = 0; k0 < HID; k0 += 32) {
        int ka = k0 + lhi * 8;
        bf16x8 af[4], bfr[2];
        #pragma unroll
        for (int mi = 0; mi < 4; ++mi) {
            size_t roff = (size_t)(m0 + wm + mi * 16 + llo) * HID + ka;
            if (XB) {
                af[mi] = *(const bf16x8*)(xb + roff);
            } else {
                f32x4 lo = *(const f32x4*)(xf + roff);
                f32x4 hi = *(const f32x4*)(xf + roff + 4);
                #pragma unroll
                for (int jj = 0; jj < 4; ++jj) { af[mi][jj] = (__bf16)lo[jj]; af[mi][4 + jj] = (__bf16)hi[jj]; }
            }
        }
        #pragma unroll
        for (int ni = 0; ni < 2; ++ni)
            bfr[ni] = *(const bf16x8*)(W + (size_t)(nb + wn + ni * 16 + llo) * wstride + ka);
        #pragma unroll
        for (int mi = 0; mi < 4; ++mi)
            #pragma unroll
            for (int ni = 0; ni < 2; ++ni)
                acc[mi][ni] = __builtin_amdgcn_mfma_f32_16x16x32_bf16(af[mi], bfr[ni], acc[mi][ni], 0, 0, 0);
    }
    #pragma unroll
    for (int ni = 0; ni < 2; ++ni) {
        int colg = n0 + wn + ni * 16 + llo;
        float bv = bias[nb + wn + ni * 16 + llo];
        #pragma unroll
        for (int mi = 0; mi < 4; ++mi) {
            #pragma unroll
            for (int i = 0; i < 4; ++i) {
                int row = m0 + wm + mi * 16 + lhi * 4 + i;
                G[(size_t)row * (3 * HID) + colg] = (__bf16)(acc[mi][ni][i] + bv);
            }
        }
    }
}

// ---------------------------------------------------------------------------
// Init: hg parity0 = bf16(prev); zero all 256 per-WG flags.
// ---------------------------------------------------------------------------
__global__ __launch_bounds__(256) void gru_init(const float* __restrict__ prev,
                                                __bf16* __restrict__ hg,
                                                unsigned* __restrict__ flags)
{
    int i = blockIdx.x * 256 + threadIdx.x;
    if (i < 256 * 32) flags[i] = 0u;
    if (i < BATCH * HID) hg[i] = (__bf16)prev[i];
}

// ---------------------------------------------------------------------------
// Phase B v5: 256 WGs x 256 threads (4 waves) -> all 256 CUs, 1 wave/SIMD.
// WG (rg,j): 16 batch rows x 16 hidden cols. Wave ks = K-quarter.
// - All 3 gates' weights for (16 cols x K-quarter) in 96 VGPRs/wave: ZERO
//   per-step LDS weight traffic (v3's 384KB/step + 5.3e7 bank conflicts gone).
// - Partials combine via 24KB double-buffered LDS gbuf; ONE syncthreads/step.
// - Cross-WG sync: v3's proven protocol — coherent h stores, vmcnt(0),
//   per-WG flag store; consumers poll only their 64 rg-peer flags.
//   WAR-safe: peer flag >= t+1 implies peer finished READING h_t, so the
//   parity buffer h_t occupies can be overwritten at step t+1 (write h_{t+2}).
// - Wave 0 tail work (out stores, G prefetch) deferred after flag store.
// ---------------------------------------------------------------------------
__global__ __launch_bounds__(256, 1) void gru_phaseB(
    const __bf16* __restrict__ Wrb, const __bf16* __restrict__ Wub,
    const __bf16* __restrict__ Wob, const float* __restrict__ bo,
    const float* __restrict__ prev, const __bf16* __restrict__ G,
    __bf16* __restrict__ hg, unsigned* __restrict__ flags,
    float* __restrict__ out)
{
    __shared__ float gbuf[2][3][4][64 * 4];   // [parity][gate][ks][lane*4]

    const int g = blockIdx.x;
    const int j = g & 63, rg = g >> 6;
    const int tid = threadIdx.x;
    const int lane = tid & 63, ks = tid >> 6;
    const int llo = lane & 15, lhi = lane >> 4;

    // ---- stage this wave's K-quarter of all 3 gate weight sets into VGPRs ----
    bf16x8 wV[3][8];
    {
        const __bf16* w0 = Wrb + (size_t)(16 * j + llo) * (2 * HID) + HID + ks * 256 + lhi * 8;
        const __bf16* w1 = Wub + (size_t)(16 * j + llo) * (2 * HID) + HID + ks * 256 + lhi * 8;
        const __bf16* w2 = Wob + (size_t)(16 * j + llo) * HID + ks * 256 + lhi * 8;
        #pragma unroll
        for (int kk = 0; kk < 8; ++kk) {
            wV[0][kk] = *(const bf16x8*)(w0 + kk * 32);
            wV[1][kk] = *(const bf16x8*)(w1 + kk * 32);
            wV[2][kk] = *(const bf16x8*)(w2 + kk * 32);
        }
    }

    // ---- wave-0 state: f32 h master + gate x-parts in registers ----
    float hf[4] = {}, pr[4] = {}, pu[4] = {}, px[4] = {};
    float bov = 0.f;
    if (ks == 0) {
        bov = bo[16 * j + llo];
        #pragma unroll
        for (int i = 0; i < 4; ++i) {
            int row = 16 * rg + lhi * 4 + i;
            hf[i] = prev[(size_t)row * HID + 16 * j + llo];
            const __bf16* Gp = G + (size_t)row * (3 * HID) + 16 * j + llo;
            pr[i] = (float)Gp[0]; pu[i] = (float)Gp[HID]; px[i] = (float)Gp[2 * HID];
        }
    }

    const unsigned* myflag = flags + (rg * 64 + lane) * 32;

    for (int t = 0; t < SEQ; ++t) {
        // ---- wait for h_t to be published by the 64 rg-peer WGs ----
        if (t > 0) {
            int guard = 0;
            for (;;) {
                unsigned v = cload_b32(myflag);
                if (__all((int)(v >= (unsigned)t))) break;
                if (++guard >= (1 << 20)) break;
            }
        }
        // ---- load h K-quarter (coherent), 8 x b128 ----
        const __bf16* hk = hg + (size_t)(t & 1) * (BATCH * HID)
                         + (size_t)(16 * rg + llo) * HID + ks * 256 + lhi * 8;
        bf16x8 hv[8];
        #pragma unroll
        for (int kk = 0; kk < 8; ++kk) cload_b128(&hv[kk], hk + kk * 32);
        vmcnt0();
        // ---- 24 MFMA: 3 gates x 8 K-blocks, weights already in VGPRs ----
        f32x4 aR = {}, aU = {}, aO = {};
        #pragma unroll
        for (int kk = 0; kk < 8; ++kk) {
            aR = __builtin_amdgcn_mfma_f32_16x16x32_bf16(hv[kk], wV[0][kk], aR, 0, 0, 0);
            aU = __builtin_amdgcn_mfma_f32_16x16x32_bf16(hv[kk], wV[1][kk], aU, 0, 0, 0);
            aO = __builtin_amdgcn_mfma_f32_16x16x32_bf16(hv[kk], wV[2][kk], aO, 0, 0, 0);
        }
        const int p = t & 1;
        *(f32x4*)&gbuf[p][0][ks][lane * 4] = aR;
        *(f32x4*)&gbuf[p][1][ks][lane * 4] = aU;
        *(f32x4*)&gbuf[p][2][ks][lane * 4] = aO;
        __syncthreads();

        if (ks == 0) {
            f32x4 sR = *(const f32x4*)&gbuf[p][0][0][lane * 4];
            f32x4 sU = *(const f32x4*)&gbuf[p][1][0][lane * 4];
            f32x4 sO = *(const f32x4*)&gbuf[p][2][0][lane * 4];
            #pragma unroll
            for (int kk = 1; kk < 4; ++kk) {
                sR += *(const f32x4*)&gbuf[p][0][kk][lane * 4];
                sU += *(const f32x4*)&gbuf[p][1][kk][lane * 4];
                sO += *(const f32x4*)&gbuf[p][2][kk][lane * 4];
            }
            __bf16* hn = hg + (size_t)((t + 1) & 1) * (BATCH * HID);
            #pragma unroll
            for (int i = 0; i < 4; ++i) {
                int row = 16 * rg + lhi * 4 + i;
                float r = sigm(sR[i] + pr[i]);
                float u = sigm(sU[i] + pu[i]);
                float c = tanh_((sO[i] + bov) * r + px[i]);
                float hnew = (1.0f - u) * c + u * hf[i];
                hf[i] = hnew;
                cstore_b16(hn + (size_t)row * HID + 16 * j + llo, (__bf16)hnew);
            }
            vmcnt0();                       // h at coherence point before flag
            cstore_b32((unsigned*)(flags + (rg * 64 + j) * 32), (unsigned)(t + 1));
            // ---- deferred: out stores + G prefetch for t+1 ----
            #pragma unroll
            for (int i = 0; i < 4; ++i) {
                int row = 16 * rg + lhi * 4 + i;
                __builtin_nontemporal_store(hf[i],
                    out + (size_t)t * (BATCH * HID) + (size_t)row * HID + 16 * j + llo);
                if (t == SEQ - 1)
                    __builtin_nontemporal_store(hf[i],
                        out + (size_t)SEQ * (BATCH * HID) + (size_t)row * HID + 16 * j + llo);
            }
            if (t + 1 < SEQ) {
                const __bf16* Gt = G + (size_t)(t + 1) * BATCH * (3 * HID);
                #pragma unroll
                for (int i = 0; i < 4; ++i) {
                    int row = 16 * rg + lhi * 4 + i;
                    const __bf16* Gp = Gt + (size_t)row * (3 * HID) + 16 * j + llo;
                    pr[i] = (float)Gp[0]; pu[i] = (float)Gp[HID]; px[i] = (float)Gp[2 * HID];
                }
            }
        }
    }
}

extern "C" void kernel_launch(void* const* d_in, const int* in_sizes, int n_in,
                              void* d_out, int out_size, void* d_ws, size_t ws_size,
                              hipStream_t stream) {
    (void)in_sizes; (void)n_in; (void)out_size;
    const float* x    = (const float*)d_in[0];
    const float* prev = (const float*)d_in[1];
    const float* Wr   = (const float*)d_in[2];
    const float* br   = (const float*)d_in[3];
    const float* Wu   = (const float*)d_in[4];
    const float* bu   = (const float*)d_in[5];
    const float* Wo   = (const float*)d_in[6];
    const float* bo   = (const float*)d_in[7];
    const float* Wx   = (const float*)d_in[8];
    const float* bx   = (const float*)d_in[9];
    float* out = (float*)d_out;

    // workspace layout (bytes)
    const size_t G_ELEMS  = (size_t)SEQ * BATCH * 3 * HID;
    const size_t WR_ELEMS = (size_t)HID * 2 * HID;
    const size_t WO_ELEMS = (size_t)HID * HID;
    char* ws = (char*)d_ws;
    size_t off = 0;
    __bf16* G   = (__bf16*)(ws + off); off += G_ELEMS * 2;
    __bf16* Wrb = (__bf16*)(ws + off); off += WR_ELEMS * 2;
    __bf16* Wub = (__bf16*)(ws + off); off += WR_ELEMS * 2;
    __bf16* Wob = (__bf16*)(ws + off); off += WO_ELEMS * 2;
    __bf16* Wxb = (__bf16*)(ws + off); off += WO_ELEMS * 2;
    __bf16* hg  = (__bf16*)(ws + off); off += (size_t)2 * BATCH * HID * 2;
    unsigned* flags = (unsigned*)(ws + off); off += 256 * 32 * 4;   // 32KB, 128B-strided
    const size_t X_ELEMS = (size_t)SEQ * BATCH * HID;
    bool use_xb = (ws_size >= off + X_ELEMS * 2);
    __bf16* xb = (__bf16*)(ws + off);

    cvt_f32_bf16<<<(int)(WR_ELEMS / 4 / 256), 256, 0, stream>>>(Wr, Wrb, (int)WR_ELEMS);
    cvt_f32_bf16<<<(int)(WR_ELEMS / 4 / 256), 256, 0, stream>>>(Wu, Wub, (int)WR_ELEMS);
    cvt_f32_bf16<<<(int)(WO_ELEMS / 4 / 256), 256, 0, stream>>>(Wo, Wob, (int)WO_ELEMS);
    cvt_f32_bf16<<<(int)(WO_ELEMS / 4 / 256), 256, 0, stream>>>(Wx, Wxb, (int)WO_ELEMS);
    if (use_xb)
        cvt_f32_bf16<<<(int)(X_ELEMS / 4 / 256), 256, 0, stream>>>(x, xb, (int)X_ELEMS);

    gru_init<<<(BATCH * HID) / 256, 256, 0, stream>>>(prev, hg, flags);

    int gridA = (SEQ * BATCH / 128) * ((3 * HID) / 64);
    if (use_xb)
        gru_phaseA<true><<<gridA, 256, 0, stream>>>(x, xb, Wrb, Wub, Wxb, br, bu, bx, G);
    else
        gru_phaseA<false><<<gridA, 256, 0, stream>>>(x, xb, Wrb, Wub, Wxb, br, bu, bx, G);

    gru_phaseB<<<256, 256, 0, stream>>>(Wrb, Wub, Wob, bo, prev, G, hg, flags, out);
}

// Round 7
// 2881.783 us; speedup vs baseline: 3.7274x; 1.1263x over previous
//
#include <hip/hip_runtime.h>
#include <hip/hip_bf16.h>

#define SEQ 512
#define BATCH 64
#define HID 1024

typedef __bf16 bf16x8 __attribute__((ext_vector_type(8)));
typedef __bf16 bf16x4 __attribute__((ext_vector_type(4)));
typedef float f32x4 __attribute__((ext_vector_type(4)));
typedef unsigned uint32x2 __attribute__((ext_vector_type(2)));

__device__ __forceinline__ float sigm(float x) { return 1.0f / (1.0f + __expf(-x)); }
__device__ __forceinline__ float tanh_(float x) { return 2.0f / (1.0f + __expf(-2.0f * x)) - 1.0f; }

// device-coherent (LLC coherence point) helpers
__device__ __forceinline__ void cload_b128(bf16x8* d, const __bf16* p) {
    asm volatile("global_load_dwordx4 %0, %1, off sc0 sc1" : "=v"(*d) : "v"(p));
}
__device__ __forceinline__ void cstore_b64(__bf16* p, bf16x4 v) {
    uint32x2 uv = __builtin_bit_cast(uint32x2, v);
    asm volatile("global_store_dwordx2 %0, %1, off sc0 sc1" :: "v"(p), "v"(uv));
}
__device__ __forceinline__ unsigned cload_b32(const unsigned* p) {
    unsigned r;
    asm volatile("global_load_dword %0, %1, off sc0 sc1\n\ts_waitcnt vmcnt(0)"
                 : "=v"(r) : "v"(p) : "memory");
    __builtin_amdgcn_sched_barrier(0);
    return r;
}
__device__ __forceinline__ void vmcnt0() {
    asm volatile("s_waitcnt vmcnt(0)" ::: "memory");
    __builtin_amdgcn_sched_barrier(0);
}

// ---------------------------------------------------------------------------
// f32 -> bf16 conversion (n multiple of 4)
// ---------------------------------------------------------------------------
__global__ __launch_bounds__(256) void cvt_f32_bf16(const float* __restrict__ src,
                                                     __bf16* __restrict__ dst, int n)
{
    int i = (blockIdx.x * 256 + threadIdx.x) * 4;
    if (i < n) {
        f32x4 v = *(const f32x4*)(src + i);
        bf16x4 o;
        #pragma unroll
        for (int j = 0; j < 4; ++j) o[j] = (__bf16)v[j];
        *(bf16x4*)(dst + i) = o;
    }
}

// ---------------------------------------------------------------------------
// Phase A v2 (m97 pattern): 128x128 tile, BK=64, global_load_lds w16,
// both-sides XOR swizzle. G[m][n], m = t*BATCH+b, n in [0,3072).
// ---------------------------------------------------------------------------
__global__ __launch_bounds__(256) void gru_phaseA2(
    const __bf16* __restrict__ xb,
    const __bf16* __restrict__ Wrb, const __bf16* __restrict__ Wub,
    const __bf16* __restrict__ Wxb,
    const float* __restrict__ br, const float* __restrict__ bu,
    const float* __restrict__ bx, __bf16* __restrict__ G)
{
    __shared__ __bf16 Al[128 * 64];
    __shared__ __bf16 Bl[128 * 64];

    const int NT = 24;  // 3072/128; 8 n-tiles per gate, never crossing a boundary
    int mt = blockIdx.x / NT, nt = blockIdx.x % NT;
    int m0 = mt * 128, n0 = nt * 128;

    const __bf16* W; const float* bias; int wstride, nb;
    if (n0 < HID)          { W = Wrb; bias = br; wstride = 2 * HID; nb = n0; }
    else if (n0 < 2 * HID) { W = Wub; bias = bu; wstride = 2 * HID; nb = n0 - HID; }
    else                   { W = Wxb; bias = bx; wstride = HID;     nb = n0 - 2 * HID; }

    const int tid = threadIdx.x;
    const int lane = tid & 63, w = tid >> 6;
    const int llo = lane & 15, lhi = lane >> 4;
    const int wm = (w & 1) * 64, wn = (w >> 1) * 64;

    f32x4 acc[4][4] = {};

    for (int k0 = 0; k0 < HID; k0 += 64) {
        __syncthreads();   // protect LDS from previous iteration's readers
        // stage A and B tiles: pre-swizzled global source, linear LDS dest
        #pragma unroll
        for (int s = 0; s < 4; ++s) {
            int idx = s * 256 + tid;
            int r = idx >> 3, c16 = idx & 7;
            int eoff = (c16 * 8) ^ ((r & 7) << 3);   // swizzled elem offset in row
            const __bf16* ga = xb + (size_t)(m0 + r) * HID + k0 + eoff;
            char* la = (char*)Al + (size_t)(s * 256 + w * 64) * 16;
            __builtin_amdgcn_global_load_lds(
                (const __attribute__((address_space(1))) void*)ga,
                (__attribute__((address_space(3))) void*)la, 16, 0, 0);
        }
        #pragma unroll
        for (int s = 0; s < 4; ++s) {
            int idx = s * 256 + tid;
            int r = idx >> 3, c16 = idx & 7;
            int eoff = (c16 * 8) ^ ((r & 7) << 3);
            const __bf16* gb = W + (size_t)(nb + r) * wstride + k0 + eoff;
            char* lb = (char*)Bl + (size_t)(s * 256 + w * 64) * 16;
            __builtin_amdgcn_global_load_lds(
                (const __attribute__((address_space(1))) void*)gb,
                (__attribute__((address_space(3))) void*)lb, 16, 0, 0);
        }
        __syncthreads();   // compiler drains vmcnt before barrier

        #pragma unroll
        for (int kk = 0; kk < 2; ++kk) {
            bf16x8 a[4], b[4];
            #pragma unroll
            for (int mi = 0; mi < 4; ++mi) {
                int row = wm + mi * 16 + llo;
                a[mi] = *(const bf16x8*)((const char*)Al + row * 128
                          + ((kk * 64 + lhi * 16) ^ ((row & 7) << 4)));
            }
            #pragma unroll
            for (int ni = 0; ni < 4; ++ni) {
                int row = wn + ni * 16 + llo;
                b[ni] = *(const bf16x8*)((const char*)Bl + row * 128
                          + ((kk * 64 + lhi * 16) ^ ((row & 7) << 4)));
            }
            #pragma unroll
            for (int mi = 0; mi < 4; ++mi)
                #pragma unroll
                for (int ni = 0; ni < 4; ++ni)
                    acc[mi][ni] = __builtin_amdgcn_mfma_f32_16x16x32_bf16(a[mi], b[ni], acc[mi][ni], 0, 0, 0);
        }
    }

    #pragma unroll
    for (int ni = 0; ni < 4; ++ni) {
        int colg = n0 + wn + ni * 16 + llo;
        float bv = bias[nb + wn + ni * 16 + llo];
        #pragma unroll
        for (int mi = 0; mi < 4; ++mi) {
            #pragma unroll
            for (int i = 0; i < 4; ++i) {
                int row = m0 + wm + mi * 16 + lhi * 4 + i;
                G[(size_t)row * (3 * HID) + colg] = (__bf16)(acc[mi][ni][i] + bv);
            }
        }
    }
}

// ---------------------------------------------------------------------------
// Phase A fallback (round-5 version) for when ws can't hold xb.
// ---------------------------------------------------------------------------
__global__ __launch_bounds__(256) void gru_phaseA_f32(
    const float* __restrict__ xf,
    const __bf16* __restrict__ Wrb, const __bf16* __restrict__ Wub,
    const __bf16* __restrict__ Wxb,
    const float* __restrict__ br, const float* __restrict__ bu,
    const float* __restrict__ bx, __bf16* __restrict__ G)
{
    const int NT = (3 * HID) / 64;
    int mt = blockIdx.x / NT;
    int nt = blockIdx.x % NT;
    int m0 = mt * 128, n0 = nt * 64;

    const __bf16* W; const float* bias; int wstride, nb;
    if (n0 < HID)          { W = Wrb; bias = br; wstride = 2 * HID; nb = n0; }
    else if (n0 < 2 * HID) { W = Wub; bias = bu; wstride = 2 * HID; nb = n0 - HID; }
    else                   { W = Wxb; bias = bx; wstride = HID;     nb = n0 - 2 * HID; }

    int lane = threadIdx.x & 63, w = threadIdx.x >> 6;
    int llo = lane & 15, lhi = lane >> 4;
    int wm = (w & 1) * 64, wn = (w >> 1) * 32;

    f32x4 acc[4][2] = {};
    #pragma unroll 2
    for (int k0 = 0; k0 < HID; k0 += 32) {
        int ka = k0 + lhi * 8;
        bf16x8 af[4], bfr[2];
        #pragma unroll
        for (int mi = 0; mi < 4; ++mi) {
            size_t roff = (size_t)(m0 + wm + mi * 16 + llo) * HID + ka;
            f32x4 lo = *(const f32x4*)(xf + roff);
            f32x4 hi = *(const f32x4*)(xf + roff + 4);
            #pragma unroll
            for (int jj = 0; jj < 4; ++jj) { af[mi][jj] = (__bf16)lo[jj]; af[mi][4 + jj] = (__bf16)hi[jj]; }
        }
        #pragma unroll
        for (int ni = 0; ni < 2; ++ni)
            bfr[ni] = *(const bf16x8*)(W + (size_t)(nb + wn + ni * 16 + llo) * wstride + ka);
        #pragma unroll
        for (int mi = 0; mi < 4; ++mi)
            #pragma unroll
            for (int ni = 0; ni < 2; ++ni)
                acc[mi][ni] = __builtin_amdgcn_mfma_f32_16x16x32_bf16(af[mi], bfr[ni], acc[mi][ni], 0, 0, 0);
    }
    #pragma unroll
    for (int ni = 0; ni < 2; ++ni) {
        int colg = n0 + wn + ni * 16 + llo;
        float bv = bias[nb + wn + ni * 16 + llo];
        #pragma unroll
        for (int mi = 0; mi < 4; ++mi) {
            #pragma unroll
            for (int i = 0; i < 4; ++i) {
                int row = m0 + wm + mi * 16 + lhi * 4 + i;
                G[(size_t)row * (3 * HID) + colg] = (__bf16)(acc[mi][ni][i] + bv);
            }
        }
    }
}

// ---------------------------------------------------------------------------
// Init: hg parity0 = bf16(prev); zero the quarter counters.
// ---------------------------------------------------------------------------
__global__ __launch_bounds__(256) void gru_init(const float* __restrict__ prev,
                                                __bf16* __restrict__ hg,
                                                unsigned* __restrict__ cnt)
{
    int i = blockIdx.x * 256 + threadIdx.x;
    if (i < 2048) cnt[i] = 0u;
    if (i < BATCH * HID) hg[i] = (__bf16)prev[i];
}

// ---------------------------------------------------------------------------
// Phase B v6: 256 WGs x 4 waves. WG (rg,j): 16 rows x 16 cols; wave ks =
// K-quarter, all-3-gate weights in 96 VGPRs (zero LDS weight traffic).
// Sync slimmed vs v5:
//  - per-(rg,quarter) atomic counter; producer j adds to cnt[rg][j>>4] after
//    coherent-store drain; consumer wave ks polls ONE shared line (1 req/wave
//    instead of 64 distinct lines/lane) for cnt >= 16*t.
//  - WAR-safe: all 4 waves' polls + syncthreads cover all 64 producers of
//    step t-1 before wave0 overwrites parity (t+1)&1.
//  - transposed epilogue: wave0 lane l owns (row=l>>2, 4 cols) -> one 8B
//    coherent h store, one 16B out store, bf16x4 G prefetch.
// ---------------------------------------------------------------------------
__global__ __launch_bounds__(256, 1) void gru_phaseB(
    const __bf16* __restrict__ Wrb, const __bf16* __restrict__ Wub,
    const __bf16* __restrict__ Wob, const float* __restrict__ bo,
    const float* __restrict__ prev, const __bf16* __restrict__ G,
    __bf16* __restrict__ hg, unsigned* __restrict__ cnt,
    float* __restrict__ out)
{
    __shared__ float gbuf[2][3][4][256];   // [parity][gate][ks][row*16+col]

    const int g = blockIdx.x;
    const int j = g & 63, rg = g >> 6;
    const int tid = threadIdx.x;
    const int lane = tid & 63, ks = tid >> 6;
    const int llo = lane & 15, lhi = lane >> 4;
    const int er = lane >> 2, cg = lane & 3;          // epilogue mapping
    const int colbase = 16 * j + cg * 4;
    const int erow = 16 * rg + er;

    // ---- stage this wave's K-quarter of all 3 gate weight sets into VGPRs ----
    bf16x8 wV[3][8];
    {
        const __bf16* w0 = Wrb + (size_t)(16 * j + llo) * (2 * HID) + HID + ks * 256 + lhi * 8;
        const __bf16* w1 = Wub + (size_t)(16 * j + llo) * (2 * HID) + HID + ks * 256 + lhi * 8;
        const __bf16* w2 = Wob + (size_t)(16 * j + llo) * HID + ks * 256 + lhi * 8;
        #pragma unroll
        for (int kk = 0; kk < 8; ++kk) {
            wV[0][kk] = *(const bf16x8*)(w0 + kk * 32);
            wV[1][kk] = *(const bf16x8*)(w1 + kk * 32);
            wV[2][kk] = *(const bf16x8*)(w2 + kk * 32);
        }
    }

    // ---- wave-0 epilogue state ----
    float hf[4] = {}, pr[4] = {}, pu[4] = {}, px[4] = {}, bov[4] = {};
    if (ks == 0) {
        f32x4 bv = *(const f32x4*)(bo + colbase);
        f32x4 hp = *(const f32x4*)(prev + (size_t)erow * HID + colbase);
        bf16x4 g0 = *(const bf16x4*)(G + (size_t)erow * (3 * HID) + colbase);
        bf16x4 g1 = *(const bf16x4*)(G + (size_t)erow * (3 * HID) + HID + colbase);
        bf16x4 g2 = *(const bf16x4*)(G + (size_t)erow * (3 * HID) + 2 * HID + colbase);
        #pragma unroll
        for (int i = 0; i < 4; ++i) {
            bov[i] = bv[i]; hf[i] = hp[i];
            pr[i] = (float)g0[i]; pu[i] = (float)g1[i]; px[i] = (float)g2[i];
        }
    }

    unsigned* cinc = cnt + (rg * 4 + (j >> 4)) * 32;        // my increment target
    const unsigned* cpoll = cnt + (rg * 4 + ks) * 32;       // my poll target

    for (int t = 0; t < SEQ; ++t) {
        // ---- wait for the 16 producers of my K-quarter to finish step t-1 ----
        if (t > 0) {
            unsigned need = 16u * (unsigned)t;
            int guard = 0;
            while (cload_b32(cpoll) < need && ++guard < (1 << 20)) {}
        }
        // ---- load h K-quarter (coherent), 8 x b128 ----
        const __bf16* hk = hg + (size_t)(t & 1) * (BATCH * HID)
                         + (size_t)(16 * rg + llo) * HID + ks * 256 + lhi * 8;
        bf16x8 hv[8];
        #pragma unroll
        for (int kk = 0; kk < 8; ++kk) cload_b128(&hv[kk], hk + kk * 32);
        vmcnt0();
        // ---- 24 MFMA: 3 gates x 8 K-blocks ----
        f32x4 aR = {}, aU = {}, aO = {};
        #pragma unroll
        for (int kk = 0; kk < 8; ++kk) {
            aR = __builtin_amdgcn_mfma_f32_16x16x32_bf16(hv[kk], wV[0][kk], aR, 0, 0, 0);
            aU = __builtin_amdgcn_mfma_f32_16x16x32_bf16(hv[kk], wV[1][kk], aU, 0, 0, 0);
            aO = __builtin_amdgcn_mfma_f32_16x16x32_bf16(hv[kk], wV[2][kk], aO, 0, 0, 0);
        }
        const int p = t & 1;
        // transposed gbuf write: [row*16+col]
        #pragma unroll
        for (int i = 0; i < 4; ++i) {
            gbuf[p][0][ks][(lhi * 4 + i) * 16 + llo] = aR[i];
            gbuf[p][1][ks][(lhi * 4 + i) * 16 + llo] = aU[i];
            gbuf[p][2][ks][(lhi * 4 + i) * 16 + llo] = aO[i];
        }
        __syncthreads();

        if (ks == 0) {
            f32x4 sR = {}, sU = {}, sO = {};
            #pragma unroll
            for (int kk = 0; kk < 4; ++kk) {
                sR += *(const f32x4*)&gbuf[p][0][kk][er * 16 + cg * 4];
                sU += *(const f32x4*)&gbuf[p][1][kk][er * 16 + cg * 4];
                sO += *(const f32x4*)&gbuf[p][2][kk][er * 16 + cg * 4];
            }
            bf16x4 hb; f32x4 ho;
            #pragma unroll
            for (int i = 0; i < 4; ++i) {
                float r = sigm(sR[i] + pr[i]);
                float u = sigm(sU[i] + pu[i]);
                float c = tanh_((sO[i] + bov[i]) * r + px[i]);
                float hnew = (1.0f - u) * c + u * hf[i];
                hf[i] = hnew; hb[i] = (__bf16)hnew; ho[i] = hnew;
            }
            __bf16* hn = hg + (size_t)((t + 1) & 1) * (BATCH * HID);
            cstore_b64(hn + (size_t)erow * HID + colbase, hb);
            vmcnt0();                       // h at coherence point before counter
            if (lane == 0)
                __hip_atomic_fetch_add(cinc, 1u, __ATOMIC_RELAXED, __HIP_MEMORY_SCOPE_AGENT);
            // ---- deferred: out stores + G prefetch for t+1 ----
            __builtin_nontemporal_store(ho,
                (f32x4*)(out + (size_t)t * (BATCH * HID) + (size_t)erow * HID + colbase));
            if (t == SEQ - 1)
                __builtin_nontemporal_store(ho,
                    (f32x4*)(out + (size_t)SEQ * (BATCH * HID) + (size_t)erow * HID + colbase));
            if (t + 1 < SEQ) {
                const __bf16* Gt = G + (size_t)(t + 1) * BATCH * (3 * HID) + (size_t)erow * (3 * HID);
                bf16x4 g0 = *(const bf16x4*)(Gt + colbase);
                bf16x4 g1 = *(const bf16x4*)(Gt + HID + colbase);
                bf16x4 g2 = *(const bf16x4*)(Gt + 2 * HID + colbase);
                #pragma unroll
                for (int i = 0; i < 4; ++i) {
                    pr[i] = (float)g0[i]; pu[i] = (float)g1[i]; px[i] = (float)g2[i];
                }
            }
        }
    }
}

extern "C" void kernel_launch(void* const* d_in, const int* in_sizes, int n_in,
                              void* d_out, int out_size, void* d_ws, size_t ws_size,
                              hipStream_t stream) {
    (void)in_sizes; (void)n_in; (void)out_size;
    const float* x    = (const float*)d_in[0];
    const float* prev = (const float*)d_in[1];
    const float* Wr   = (const float*)d_in[2];
    const float* br   = (const float*)d_in[3];
    const float* Wu   = (const float*)d_in[4];
    const float* bu   = (const float*)d_in[5];
    const float* Wo   = (const float*)d_in[6];
    const float* bo   = (const float*)d_in[7];
    const float* Wx   = (const float*)d_in[8];
    const float* bx   = (const float*)d_in[9];
    float* out = (float*)d_out;

    // workspace layout (bytes)
    const size_t G_ELEMS  = (size_t)SEQ * BATCH * 3 * HID;
    const size_t WR_ELEMS = (size_t)HID * 2 * HID;
    const size_t WO_ELEMS = (size_t)HID * HID;
    char* ws = (char*)d_ws;
    size_t off = 0;
    __bf16* G   = (__bf16*)(ws + off); off += G_ELEMS * 2;
    __bf16* Wrb = (__bf16*)(ws + off); off += WR_ELEMS * 2;
    __bf16* Wub = (__bf16*)(ws + off); off += WR_ELEMS * 2;
    __bf16* Wob = (__bf16*)(ws + off); off += WO_ELEMS * 2;
    __bf16* Wxb = (__bf16*)(ws + off); off += WO_ELEMS * 2;
    __bf16* hg  = (__bf16*)(ws + off); off += (size_t)2 * BATCH * HID * 2;
    unsigned* cnt = (unsigned*)(ws + off); off += 2048 * 4;
    const size_t X_ELEMS = (size_t)SEQ * BATCH * HID;
    bool use_xb = (ws_size >= off + X_ELEMS * 2);
    __bf16* xb = (__bf16*)(ws + off);

    cvt_f32_bf16<<<(int)(WR_ELEMS / 4 / 256), 256, 0, stream>>>(Wr, Wrb, (int)WR_ELEMS);
    cvt_f32_bf16<<<(int)(WR_ELEMS / 4 / 256), 256, 0, stream>>>(Wu, Wub, (int)WR_ELEMS);
    cvt_f32_bf16<<<(int)(WO_ELEMS / 4 / 256), 256, 0, stream>>>(Wo, Wob, (int)WO_ELEMS);
    cvt_f32_bf16<<<(int)(WO_ELEMS / 4 / 256), 256, 0, stream>>>(Wx, Wxb, (int)WO_ELEMS);
    if (use_xb)
        cvt_f32_bf16<<<(int)(X_ELEMS / 4 / 256), 256, 0, stream>>>(x, xb, (int)X_ELEMS);

    gru_init<<<(BATCH * HID) / 256, 256, 0, stream>>>(prev, hg, cnt);

    if (use_xb) {
        gru_phaseA2<<<256 * 24, 256, 0, stream>>>(xb, Wrb, Wub, Wxb, br, bu, bx, G);
    } else {
        int gridA = (SEQ * BATCH / 128) * ((3 * HID) / 64);
        gru_phaseA_f32<<<gridA, 256, 0, stream>>>(x, Wrb, Wub, Wxb, br, bu, bx, G);
    }

    gru_phaseB<<<256, 256, 0, stream>>>(Wrb, Wub, Wob, bo, prev, G, hg, cnt, out);
}

// Round 8
// 2272.945 us; speedup vs baseline: 4.7259x; 1.2679x over previous
//
#include <hip/hip_runtime.h>
#include <hip/hip_bf16.h>

#define SEQ 512
#define BATCH 64
#define HID 1024

typedef __bf16 bf16x8 __attribute__((ext_vector_type(8)));
typedef __bf16 bf16x4 __attribute__((ext_vector_type(4)));
typedef float f32x4 __attribute__((ext_vector_type(4)));

__device__ __forceinline__ float sigm(float x) { return 1.0f / (1.0f + __expf(-x)); }
__device__ __forceinline__ float tanh_(float x) { return 2.0f / (1.0f + __expf(-2.0f * x)) - 1.0f; }

// device-coherent (LLC coherence point) helpers
__device__ __forceinline__ void cload_b128(bf16x8* d, const __bf16* p) {
    asm volatile("global_load_dwordx4 %0, %1, off sc0 sc1" : "=v"(*d) : "v"(p));
}
__device__ __forceinline__ void cstore_b16(__bf16* p, __bf16 v) {
    unsigned short uv = __builtin_bit_cast(unsigned short, v);
    asm volatile("global_store_short %0, %1, off sc0 sc1" :: "v"(p), "v"(uv));
}
__device__ __forceinline__ void cstore_b32(unsigned* p, unsigned v) {
    asm volatile("global_store_dword %0, %1, off sc0 sc1" :: "v"(p), "v"(v));
}
__device__ __forceinline__ unsigned cload_b32(const unsigned* p) {
    unsigned r;
    asm volatile("global_load_dword %0, %1, off sc0 sc1\n\ts_waitcnt vmcnt(0)"
                 : "=v"(r) : "v"(p) : "memory");
    __builtin_amdgcn_sched_barrier(0);
    return r;
}
__device__ __forceinline__ void vmcnt0() {
    asm volatile("s_waitcnt vmcnt(0)" ::: "memory");
    __builtin_amdgcn_sched_barrier(0);
}

// ---------------------------------------------------------------------------
// f32 -> bf16 conversion (n multiple of 4)
// ---------------------------------------------------------------------------
__global__ __launch_bounds__(256) void cvt_f32_bf16(const float* __restrict__ src,
                                                     __bf16* __restrict__ dst, int n)
{
    int i = (blockIdx.x * 256 + threadIdx.x) * 4;
    if (i < n) {
        f32x4 v = *(const f32x4*)(src + i);
        bf16x4 o;
        #pragma unroll
        for (int j = 0; j < 4; ++j) o[j] = (__bf16)v[j];
        *(bf16x4*)(dst + i) = o;
    }
}

// ---------------------------------------------------------------------------
// G layout (tile-blocked for phaseB): element index
//   E(t, rg, j, gate, r8, c16) = (((t*8+rg)*64 + j)*3 + gate)*128 + r8*16 + c16
// where b = rg*8 + r8 (batch row), col = j*16 + c16 (col within gate).
// Each (t,rg,j) block is 768B contiguous -> phaseB reads it with one
// 48-lane global_load_lds, zero overfetch.
// ---------------------------------------------------------------------------

// ---------------------------------------------------------------------------
// Phase A v2 (m97 pattern): 128x128 tile, BK=64, global_load_lds w16,
// both-sides XOR swizzle; epilogue writes tile-blocked G.
// ---------------------------------------------------------------------------
__global__ __launch_bounds__(256) void gru_phaseA2(
    const __bf16* __restrict__ xb,
    const __bf16* __restrict__ Wrb, const __bf16* __restrict__ Wub,
    const __bf16* __restrict__ Wxb,
    const float* __restrict__ br, const float* __restrict__ bu,
    const float* __restrict__ bx, __bf16* __restrict__ G)
{
    __shared__ __bf16 Al[128 * 64];
    __shared__ __bf16 Bl[128 * 64];

    const int NT = 24;
    int mt = blockIdx.x / NT, nt = blockIdx.x % NT;
    int m0 = mt * 128, n0 = nt * 128;

    const __bf16* W; const float* bias; int wstride, nb, gate;
    if (n0 < HID)          { W = Wrb; bias = br; wstride = 2 * HID; nb = n0;           gate = 0; }
    else if (n0 < 2 * HID) { W = Wub; bias = bu; wstride = 2 * HID; nb = n0 - HID;     gate = 1; }
    else                   { W = Wxb; bias = bx; wstride = HID;     nb = n0 - 2 * HID; gate = 2; }

    const int tid = threadIdx.x;
    const int lane = tid & 63, w = tid >> 6;
    const int llo = lane & 15, lhi = lane >> 4;
    const int wm = (w & 1) * 64, wn = (w >> 1) * 64;

    f32x4 acc[4][4] = {};

    for (int k0 = 0; k0 < HID; k0 += 64) {
        __syncthreads();
        #pragma unroll
        for (int s = 0; s < 4; ++s) {
            int idx = s * 256 + tid;
            int r = idx >> 3, c16 = idx & 7;
            int eoff = (c16 * 8) ^ ((r & 7) << 3);
            const __bf16* ga = xb + (size_t)(m0 + r) * HID + k0 + eoff;
            char* la = (char*)Al + (size_t)(s * 256 + w * 64) * 16;
            __builtin_amdgcn_global_load_lds(
                (const __attribute__((address_space(1))) void*)ga,
                (__attribute__((address_space(3))) void*)la, 16, 0, 0);
        }
        #pragma unroll
        for (int s = 0; s < 4; ++s) {
            int idx = s * 256 + tid;
            int r = idx >> 3, c16 = idx & 7;
            int eoff = (c16 * 8) ^ ((r & 7) << 3);
            const __bf16* gb = W + (size_t)(nb + r) * wstride + k0 + eoff;
            char* lb = (char*)Bl + (size_t)(s * 256 + w * 64) * 16;
            __builtin_amdgcn_global_load_lds(
                (const __attribute__((address_space(1))) void*)gb,
                (__attribute__((address_space(3))) void*)lb, 16, 0, 0);
        }
        __syncthreads();

        #pragma unroll
        for (int kk = 0; kk < 2; ++kk) {
            bf16x8 a[4], b[4];
            #pragma unroll
            for (int mi = 0; mi < 4; ++mi) {
                int row = wm + mi * 16 + llo;
                a[mi] = *(const bf16x8*)((const char*)Al + row * 128
                          + ((kk * 64 + lhi * 16) ^ ((row & 7) << 4)));
            }
            #pragma unroll
            for (int ni = 0; ni < 4; ++ni) {
                int row = wn + ni * 16 + llo;
                b[ni] = *(const bf16x8*)((const char*)Bl + row * 128
                          + ((kk * 64 + lhi * 16) ^ ((row & 7) << 4)));
            }
            #pragma unroll
            for (int mi = 0; mi < 4; ++mi)
                #pragma unroll
                for (int ni = 0; ni < 4; ++ni)
                    acc[mi][ni] = __builtin_amdgcn_mfma_f32_16x16x32_bf16(a[mi], b[ni], acc[mi][ni], 0, 0, 0);
        }
    }

    #pragma unroll
    for (int ni = 0; ni < 4; ++ni) {
        int cg0 = nb + wn + ni * 16;      // col-in-gate base (multiple of 16)
        int jn = cg0 >> 4;
        float bv = bias[cg0 + llo];
        #pragma unroll
        for (int mi = 0; mi < 4; ++mi) {
            #pragma unroll
            for (int i = 0; i < 4; ++i) {
                int m = m0 + wm + mi * 16 + lhi * 4 + i;
                int tt = m >> 6, b = m & 63;
                size_t addr = ((((size_t)tt * 8 + (b >> 3)) * 64 + jn) * 3 + gate) * 128
                            + (b & 7) * 16 + llo;
                G[addr] = (__bf16)(acc[mi][ni][i] + bv);
            }
        }
    }
}

// ---------------------------------------------------------------------------
// Phase A fallback (f32 x on the fly), tile-blocked G epilogue.
// ---------------------------------------------------------------------------
__global__ __launch_bounds__(256) void gru_phaseA_f32(
    const float* __restrict__ xf,
    const __bf16* __restrict__ Wrb, const __bf16* __restrict__ Wub,
    const __bf16* __restrict__ Wxb,
    const float* __restrict__ br, const float* __restrict__ bu,
    const float* __restrict__ bx, __bf16* __restrict__ G)
{
    const int NT = (3 * HID) / 64;
    int mt = blockIdx.x / NT;
    int nt = blockIdx.x % NT;
    int m0 = mt * 128, n0 = nt * 64;

    const __bf16* W; const float* bias; int wstride, nb, gate;
    if (n0 < HID)          { W = Wrb; bias = br; wstride = 2 * HID; nb = n0;           gate = 0; }
    else if (n0 < 2 * HID) { W = Wub; bias = bu; wstride = 2 * HID; nb = n0 - HID;     gate = 1; }
    else                   { W = Wxb; bias = bx; wstride = HID;     nb = n0 - 2 * HID; gate = 2; }

    int lane = threadIdx.x & 63, w = threadIdx.x >> 6;
    int llo = lane & 15, lhi = lane >> 4;
    int wm = (w & 1) * 64, wn = (w >> 1) * 32;

    f32x4 acc[4][2] = {};
    #pragma unroll 2
    for (int k0 = 0; k0 < HID; k0 += 32) {
        int ka = k0 + lhi * 8;
        bf16x8 af[4], bfr[2];
        #pragma unroll
        for (int mi = 0; mi < 4; ++mi) {
            size_t roff = (size_t)(m0 + wm + mi * 16 + llo) * HID + ka;
            f32x4 lo = *(const f32x4*)(xf + roff);
            f32x4 hi = *(const f32x4*)(xf + roff + 4);
            #pragma unroll
            for (int jj = 0; jj < 4; ++jj) { af[mi][jj] = (__bf16)lo[jj]; af[mi][4 + jj] = (__bf16)hi[jj]; }
        }
        #pragma unroll
        for (int ni = 0; ni < 2; ++ni)
            bfr[ni] = *(const bf16x8*)(W + (size_t)(nb + wn + ni * 16 + llo) * wstride + ka);
        #pragma unroll
        for (int mi = 0; mi < 4; ++mi)
            #pragma unroll
            for (int ni = 0; ni < 2; ++ni)
                acc[mi][ni] = __builtin_amdgcn_mfma_f32_16x16x32_bf16(af[mi], bfr[ni], acc[mi][ni], 0, 0, 0);
    }
    #pragma unroll
    for (int ni = 0; ni < 2; ++ni) {
        int cg0 = nb + wn + ni * 16;
        int jn = cg0 >> 4;
        float bv = bias[cg0 + llo];
        #pragma unroll
        for (int mi = 0; mi < 4; ++mi) {
            #pragma unroll
            for (int i = 0; i < 4; ++i) {
                int m = m0 + wm + mi * 16 + lhi * 4 + i;
                int tt = m >> 6, b = m & 63;
                size_t addr = ((((size_t)tt * 8 + (b >> 3)) * 64 + jn) * 3 + gate) * 128
                            + (b & 7) * 16 + llo;
                G[addr] = (__bf16)(acc[mi][ni][i] + bv);
            }
        }
    }
}

// ---------------------------------------------------------------------------
// Init: hg parity0 = bf16(prev); zero the 512 per-WG flags (128B-strided).
// ---------------------------------------------------------------------------
__global__ __launch_bounds__(256) void gru_init(const float* __restrict__ prev,
                                                __bf16* __restrict__ hg,
                                                unsigned* __restrict__ flags)
{
    int i = blockIdx.x * 256 + threadIdx.x;
    if (i < 512 * 32) flags[i] = 0u;
    if (i < BATCH * HID) hg[i] = (__bf16)prev[i];
}

// ---------------------------------------------------------------------------
// Phase B v7: 512 WGs x 4 waves -> 2 WGs/CU, 2 waves/SIMD from DIFFERENT
// recurrent chains (8 independent chains of 8 batch rows each).
// WG (rg,j): 8 rows x 16 cols. Wave ks = K-quarter; all-3-gate weights for
// (16 cols x 256 K) in 96 VGPRs. MFMA A-frag duplicates rows (llo&7).
// Sync (v5-proven, slimmed): per-WG flag on own 128B line, plain coherent
// store; consumer polls the 16 producer lines of its K-quarter in ONE load.
// Epilogue parallel across all 4 waves (1 value/lane, lanes<32), h-store
// drain via syncthreads, then single flag store. G prefetched per step as
// one contiguous 768B block via global_load_lds (zero overfetch).
// ---------------------------------------------------------------------------
__global__ __launch_bounds__(256, 2) void gru_phaseB(
    const __bf16* __restrict__ Wrb, const __bf16* __restrict__ Wub,
    const __bf16* __restrict__ Wob, const float* __restrict__ bo,
    const float* __restrict__ prev, const __bf16* __restrict__ G,
    __bf16* __restrict__ hg, unsigned* __restrict__ flags,
    float* __restrict__ out)
{
    __shared__ float gbuf[2][3][4][128];   // [parity][gate][ks][r8*16+c16] 12KB
    __shared__ __bf16 Gld[2][384];         // [parity][gate*128 + r8*16+c16] 1.5KB

    const int gwg = blockIdx.x;
    const int j = gwg & 63, rg = gwg >> 6;
    const int tid = threadIdx.x;
    const int lane = tid & 63, ks = tid >> 6;
    const int llo = lane & 15, lhi = lane >> 4;

    // ---- stage this wave's K-quarter of all 3 gate weight sets into VGPRs ----
    bf16x8 wV[3][8];
    {
        const __bf16* w0 = Wrb + (size_t)(16 * j + llo) * (2 * HID) + HID + ks * 256 + lhi * 8;
        const __bf16* w1 = Wub + (size_t)(16 * j + llo) * (2 * HID) + HID + ks * 256 + lhi * 8;
        const __bf16* w2 = Wob + (size_t)(16 * j + llo) * HID + ks * 256 + lhi * 8;
        #pragma unroll
        for (int kk = 0; kk < 8; ++kk) {
            wV[0][kk] = *(const bf16x8*)(w0 + kk * 32);
            wV[1][kk] = *(const bf16x8*)(w1 + kk * 32);
            wV[2][kk] = *(const bf16x8*)(w2 + kk * 32);
        }
    }

    // ---- epilogue lane state: wave ks owns rows {2ks, 2ks+1}; lanes<32 ----
    const int erow = 2 * ks + ((lane >> 4) & 1);
    const int ecol = lane & 15;
    float hf = 0.f, bov = 0.f;
    if (lane < 32) {
        hf = prev[(size_t)(8 * rg + erow) * HID + 16 * j + ecol];
        bov = bo[16 * j + ecol];
    }

    // ---- prologue: prefetch G block for t=0 ----
    if (ks == 0 && lane < 48) {
        const __bf16* gsrc = G + (((size_t)0 * 8 + rg) * 64 + j) * 384 + lane * 8;
        __builtin_amdgcn_global_load_lds(
            (const __attribute__((address_space(1))) void*)gsrc,
            (__attribute__((address_space(3))) void*)((char*)&Gld[0][0] + lane * 16),
            16, 0, 0);
    }

    for (int t = 0; t < SEQ; ++t) {
        const int p = t & 1;
        // ---- poll: the 16 producers of my K-quarter must have published h_t ----
        if (t > 0) {
            const unsigned* fp = flags + (size_t)(rg * 64 + 16 * ks + llo) * 32;
            int guard = 0;
            for (;;) {
                unsigned v = cload_b32(fp);
                if (__all((int)(v >= (unsigned)t))) break;
                if (++guard >= (1 << 20)) break;
            }
        }
        // ---- load h K-quarter (rows duplicated llo&7), 8 x b128 coherent ----
        const __bf16* hk = hg + (size_t)p * (BATCH * HID)
                         + (size_t)(8 * rg + (llo & 7)) * HID + ks * 256 + lhi * 8;
        bf16x8 hv[8];
        #pragma unroll
        for (int kk = 0; kk < 8; ++kk) cload_b128(&hv[kk], hk + kk * 32);
        vmcnt0();
        // ---- 24 MFMA: 3 gates x 8 K-blocks ----
        f32x4 aR = {}, aU = {}, aO = {};
        #pragma unroll
        for (int kk = 0; kk < 8; ++kk) {
            aR = __builtin_amdgcn_mfma_f32_16x16x32_bf16(hv[kk], wV[0][kk], aR, 0, 0, 0);
            aU = __builtin_amdgcn_mfma_f32_16x16x32_bf16(hv[kk], wV[1][kk], aU, 0, 0, 0);
            aO = __builtin_amdgcn_mfma_f32_16x16x32_bf16(hv[kk], wV[2][kk], aO, 0, 0, 0);
        }
        // ---- partials to gbuf (unique rows 0..7 only) ----
        if (lhi < 2) {
            #pragma unroll
            for (int i = 0; i < 4; ++i) {
                gbuf[p][0][ks][(lhi * 4 + i) * 16 + llo] = aR[i];
                gbuf[p][1][ks][(lhi * 4 + i) * 16 + llo] = aU[i];
                gbuf[p][2][ks][(lhi * 4 + i) * 16 + llo] = aO[i];
            }
        }
        __syncthreads();   // bar1: gbuf + Gld[p] ready

        // ---- parallel epilogue: every wave, lanes<32, one (row,col) each ----
        float hnew = 0.f;
        if (lane < 32) {
            int idx = erow * 16 + ecol;
            float sR = gbuf[p][0][0][idx] + gbuf[p][0][1][idx] + gbuf[p][0][2][idx] + gbuf[p][0][3][idx];
            float sU = gbuf[p][1][0][idx] + gbuf[p][1][1][idx] + gbuf[p][1][2][idx] + gbuf[p][1][3][idx];
            float sO = gbuf[p][2][0][idx] + gbuf[p][2][1][idx] + gbuf[p][2][2][idx] + gbuf[p][2][3][idx];
            float gr = (float)Gld[p][0 * 128 + idx];
            float gu = (float)Gld[p][1 * 128 + idx];
            float gx = (float)Gld[p][2 * 128 + idx];
            float r = sigm(sR + gr);
            float u = sigm(sU + gu);
            float c = tanh_((sO + bov) * r + gx);
            hnew = (1.0f - u) * c + u * hf;
            hf = hnew;
            cstore_b16(hg + (size_t)(p ^ 1) * (BATCH * HID)
                          + (size_t)(8 * rg + erow) * HID + 16 * j + ecol, (__bf16)hnew);
        }
        __syncthreads();   // bar2: drains ALL waves' h stores to coherence point
        if (tid == 0)
            cstore_b32(flags + (size_t)(rg * 64 + j) * 32, (unsigned)(t + 1));
        // ---- deferred (overlaps peers' polling): G(t+1) prefetch + out ----
        if (ks == 0 && lane < 48 && t + 1 < SEQ) {
            const __bf16* gsrc = G + (((size_t)(t + 1) * 8 + rg) * 64 + j) * 384 + lane * 8;
            __builtin_amdgcn_global_load_lds(
                (const __attribute__((address_space(1))) void*)gsrc,
                (__attribute__((address_space(3))) void*)((char*)&Gld[p ^ 1][0] + lane * 16),
                16, 0, 0);
        }
        if (lane < 32) {
            __builtin_nontemporal_store(hnew,
                out + ((size_t)t * BATCH + 8 * rg + erow) * HID + 16 * j + ecol);
            if (t == SEQ - 1)
                __builtin_nontemporal_store(hnew,
                    out + ((size_t)SEQ * BATCH + 8 * rg + erow) * HID + 16 * j + ecol);
        }
    }
}

extern "C" void kernel_launch(void* const* d_in, const int* in_sizes, int n_in,
                              void* d_out, int out_size, void* d_ws, size_t ws_size,
                              hipStream_t stream) {
    (void)in_sizes; (void)n_in; (void)out_size;
    const float* x    = (const float*)d_in[0];
    const float* prev = (const float*)d_in[1];
    const float* Wr   = (const float*)d_in[2];
    const float* br   = (const float*)d_in[3];
    const float* Wu   = (const float*)d_in[4];
    const float* bu   = (const float*)d_in[5];
    const float* Wo   = (const float*)d_in[6];
    const float* bo   = (const float*)d_in[7];
    const float* Wx   = (const float*)d_in[8];
    const float* bx   = (const float*)d_in[9];
    float* out = (float*)d_out;

    // workspace layout (bytes)
    const size_t G_ELEMS  = (size_t)SEQ * BATCH * 3 * HID;
    const size_t WR_ELEMS = (size_t)HID * 2 * HID;
    const size_t WO_ELEMS = (size_t)HID * HID;
    char* ws = (char*)d_ws;
    size_t off = 0;
    __bf16* G   = (__bf16*)(ws + off); off += G_ELEMS * 2;
    __bf16* Wrb = (__bf16*)(ws + off); off += WR_ELEMS * 2;
    __bf16* Wub = (__bf16*)(ws + off); off += WR_ELEMS * 2;
    __bf16* Wob = (__bf16*)(ws + off); off += WO_ELEMS * 2;
    __bf16* Wxb = (__bf16*)(ws + off); off += WO_ELEMS * 2;
    __bf16* hg  = (__bf16*)(ws + off); off += (size_t)2 * BATCH * HID * 2;
    unsigned* flags = (unsigned*)(ws + off); off += 512 * 32 * 4;   // 64KB
    const size_t X_ELEMS = (size_t)SEQ * BATCH * HID;
    bool use_xb = (ws_size >= off + X_ELEMS * 2);
    __bf16* xb = (__bf16*)(ws + off);

    cvt_f32_bf16<<<(int)(WR_ELEMS / 4 / 256), 256, 0, stream>>>(Wr, Wrb, (int)WR_ELEMS);
    cvt_f32_bf16<<<(int)(WR_ELEMS / 4 / 256), 256, 0, stream>>>(Wu, Wub, (int)WR_ELEMS);
    cvt_f32_bf16<<<(int)(WO_ELEMS / 4 / 256), 256, 0, stream>>>(Wo, Wob, (int)WO_ELEMS);
    cvt_f32_bf16<<<(int)(WO_ELEMS / 4 / 256), 256, 0, stream>>>(Wx, Wxb, (int)WO_ELEMS);
    if (use_xb)
        cvt_f32_bf16<<<(int)(X_ELEMS / 4 / 256), 256, 0, stream>>>(x, xb, (int)X_ELEMS);

    gru_init<<<(BATCH * HID) / 256, 256, 0, stream>>>(prev, hg, flags);

    if (use_xb) {
        gru_phaseA2<<<256 * 24, 256, 0, stream>>>(xb, Wrb, Wub, Wxb, br, bu, bx, G);
    } else {
        int gridA = (SEQ * BATCH / 128) * ((3 * HID) / 64);
        gru_phaseA_f32<<<gridA, 256, 0, stream>>>(x, Wrb, Wub, Wxb, br, bu, bx, G);
    }

    gru_phaseB<<<512, 256, 0, stream>>>(Wrb, Wub, Wob, bo, prev, G, hg, flags, out);
}